// Round 4
// baseline (426.588 us; speedup 1.0000x reference)
//
#include <hip/hip_runtime.h>
#include <math.h>

// (B,H,S,D) = (2,16,2048,64), fp32 in/out. Outputs: ctx [B,H,S,D] ++ attn [B,H,S,S].
#define B_   2
#define H_   16
#define S_   2048
#define D_   64
#define QT   16
#define NQT  (S_/QT)        // 128
#define NBLK (B_*H_*NQT)    // 4096

typedef __attribute__((ext_vector_type(8))) short  bf16x8;
typedef __attribute__((ext_vector_type(8))) unsigned short u16x8;
typedef __attribute__((ext_vector_type(4))) float  f32x4;

static __device__ __forceinline__ short f2bf(float f) {
    union { float f; unsigned u; } x; x.f = f;
    unsigned r = x.u + 0x7fffu + ((x.u >> 16) & 1u);   // RNE
    return (short)(r >> 16);
}
static __device__ __forceinline__ unsigned pk_bf16(float lo, float hi) {
    unsigned r;
    asm("v_cvt_pk_bf16_f32 %0, %1, %2" : "=v"(r) : "v"(lo), "v"(hi));
    return r;
}

// ---------- pre-pass: fp32 -> bf16 with scale (Q: 0.125, K: 1.0) ----------
__global__ __launch_bounds__(256) void cvt_scale_kernel(const float* __restrict__ src,
                                                        unsigned short* __restrict__ dst,
                                                        float scale) {
    const size_t i = ((size_t)blockIdx.x * 256 + threadIdx.x) * 8;
    const float4 a = *(const float4*)(src + i);
    const float4 b = *(const float4*)(src + i + 4);
    u16x8 o;
    o[0]=f2bf(a.x*scale); o[1]=f2bf(a.y*scale); o[2]=f2bf(a.z*scale); o[3]=f2bf(a.w*scale);
    o[4]=f2bf(b.x*scale); o[5]=f2bf(b.y*scale); o[6]=f2bf(b.z*scale); o[7]=f2bf(b.w*scale);
    *(u16x8*)(dst + i) = o;
}

// ---------- pre-pass: V fp32 [bh][k][d] -> bf16 transposed Vt [bh][d][k] ----------
__global__ __launch_bounds__(256) void cvtVT_kernel(const float* __restrict__ V,
                                                    unsigned short* __restrict__ Vt) {
    const int l  = threadIdx.x & 63;
    const int w  = threadIdx.x >> 6;
    const int bh = blockIdx.x >> 6;
    const int kc = (blockIdx.x & 63) * 32 + w * 8;
    const float* vp = V + ((size_t)bh * S_ + kc) * D_ + l;
    u16x8 o;
    #pragma unroll
    for (int j = 0; j < 8; ++j) o[j] = f2bf(vp[(size_t)j * D_]);
    *(u16x8*)(Vt + ((size_t)bh * D_ + l) * S_ + kc) = o;
}

// ---------- pre-pass: mask int32 -> bitmask ----------
__global__ __launch_bounds__(256) void maskbits_kernel(const int* __restrict__ M,
                                                       unsigned long long* __restrict__ bits) {
    const int w = threadIdx.x >> 6, l = threadIdx.x & 63;
    const size_t wl0 = (size_t)(blockIdx.x * 4 + w) * 32;
    for (int it = 0; it < 32; ++it) {
        const int mk = M[(wl0 + it) * 64 + l];
        const unsigned long long bm = __ballot(mk != 0);
        if (l == 0) bits[wl0 + it] = bm;
    }
}

// Two-pass registers-only fused attention.
// Block = 256 thr = 4 waves, q-tile of 16 rows. Wave w owns keys [512w, 512w+512).
// Swapped QK^T: C = mfma(A=K, B=Q^T) -> lane (x=l&15 [q], g=l>>4) holds
// scores for keys 16*ktg + 4g + r (r=0..3), row q0+x.
// Pass A: online (m, sum) in regs; shfl_xor combine over g; 512B LDS cross-wave.
// Pass B: recompute QK^T, p = exp(s-M)*il; float4 attn store; cvt_pk + 8 shfl
// per 32-key slice builds the PV A-fragment; mfma(P, V) accumulates ctx.
// ctx cross-wave reduce via 17KB LDS strips. Total LDS ~22KB.
template<int PREP>
__global__ __launch_bounds__(256, 4)
void sdpa_2pass_kernel(const float* __restrict__ Qf, const float* __restrict__ Kf,
                       const float* __restrict__ Vf, const int* __restrict__ Mi,
                       const unsigned short* __restrict__ Qs,
                       const unsigned short* __restrict__ Kb,
                       const unsigned short* __restrict__ Vt,
                       const unsigned* __restrict__ bits,
                       float* __restrict__ ctx_out, float* __restrict__ attn_out) {
    __shared__ unsigned mb[QT][66];      // mask bits tile (padded), 4224 B
    __shared__ float red[4][QT][2];      // per-wave (m, sum), 512 B
    __shared__ float ctxp[4][QT][68];    // per-wave ctx partials (padded), 17408 B

    const int t = threadIdx.x;
    const int w = t >> 6;
    const int l = t & 63;
    const int x = l & 15;    // q (B/C col) ; also key-row for A ; d-col for PV C
    const int g = l >> 4;    // 0..3

    const int orig = blockIdx.x;
    const int swz  = (orig & 7) * (NBLK / 8) + (orig >> 3);
    const int bh   = swz >> 7;
    const int qt   = swz & 127;
    const int b    = bh >> 4;
    const int q0   = qt * QT;

    if (PREP) {
        #pragma unroll
        for (int i = 0; i < 4; ++i) {
            const int flat = t * 4 + i;
            mb[flat >> 6][flat & 63] =
                bits[((size_t)b * S_ + q0 + (flat >> 6)) * 64 + (flat & 63)];
        }
    }

    // ---- Q B-fragments (col = q = x, k(d) = 8g+j / 32+8g+j) ----
    bf16x8 bq0, bq1;
    if (PREP) {
        const unsigned short* qp = Qs + ((size_t)bh * S_ + q0 + x) * D_ + g * 8;
        bq0 = *(const bf16x8*)qp;
        bq1 = *(const bf16x8*)(qp + 32);
    } else {
        const float* qp = Qf + ((size_t)bh * S_ + q0 + x) * D_ + g * 8;
        #pragma unroll
        for (int j = 0; j < 8; ++j) bq0[j] = f2bf(0.125f * qp[j]);
        #pragma unroll
        for (int j = 0; j < 8; ++j) bq1[j] = f2bf(0.125f * qp[32 + j]);
    }
    if (PREP) __syncthreads();   // mb ready

    // masked score tile for key-tile ktg: c[r] = S[16ktg+4g+r][q0+x]
    auto qk_tile = [&](int ktg, f32x4& c) {
        bf16x8 ak0, ak1;
        if (PREP) {
            const unsigned short* kp = Kb + ((size_t)bh * S_ + ktg * 16 + x) * D_ + g * 8;
            ak0 = *(const bf16x8*)kp;
            ak1 = *(const bf16x8*)(kp + 32);
        } else {
            const float* kp = Kf + ((size_t)bh * S_ + ktg * 16 + x) * D_ + g * 8;
            #pragma unroll
            for (int j = 0; j < 8; ++j) ak0[j] = f2bf(kp[j]);
            #pragma unroll
            for (int j = 0; j < 8; ++j) ak1[j] = f2bf(kp[32 + j]);
        }
        c[0]=0.f; c[1]=0.f; c[2]=0.f; c[3]=0.f;
        c = __builtin_amdgcn_mfma_f32_16x16x32_bf16(ak0, bq0, c, 0, 0, 0);
        c = __builtin_amdgcn_mfma_f32_16x16x32_bf16(ak1, bq1, c, 0, 0, 0);
        if (PREP) {
            const unsigned word = mb[x][ktg >> 1];
            const int base = 16 * (ktg & 1) + 4 * g;
            #pragma unroll
            for (int r = 0; r < 4; ++r)
                if (!((word >> (base + r)) & 1u)) c[r] = -1e9f;
        } else {
            const int* mp = Mi + ((size_t)b * S_ + q0 + x) * S_ + ktg * 16 + 4 * g;
            #pragma unroll
            for (int r = 0; r < 4; ++r)
                if (!mp[r]) c[r] = -1e9f;
        }
    };

    // ---- Pass A: online (m, sum) ----
    float m = -INFINITY, ssum = 0.f;
    for (int kt = 0; kt < 32; ++kt) {
        f32x4 c; qk_tile(32 * w + kt, c);
        const float tm = fmaxf(fmaxf(c[0], c[1]), fmaxf(c[2], c[3]));
        const float nm = fmaxf(m, tm);
        ssum = ssum * __expf(m - nm)
             + __expf(c[0] - nm) + __expf(c[1] - nm)
             + __expf(c[2] - nm) + __expf(c[3] - nm);
        m = nm;
    }
    #pragma unroll
    for (int off = 16; off <= 32; off <<= 1) {    // combine across g
        const float mo = __shfl_xor(m, off), so = __shfl_xor(ssum, off);
        const float nm = fmaxf(m, mo);
        ssum = ssum * __expf(m - nm) + so * __expf(mo - nm);
        m = nm;
    }
    if (l < 16) { red[w][l][0] = m; red[w][l][1] = ssum; }
    __syncthreads();
    float M = -INFINITY, S = 0.f;
    #pragma unroll
    for (int wv = 0; wv < 4; ++wv) {              // combine across waves
        const float mo = red[wv][x][0], so = red[wv][x][1];
        const float nm = fmaxf(M, mo);
        S = S * __expf(M - nm) + so * __expf(mo - nm);
        M = nm;
    }
    const float il = 1.0f / S;

    // ---- Pass B: recompute, write attn, accumulate PV ----
    f32x4 ctx[4];
    #pragma unroll
    for (int ds = 0; ds < 4; ++ds) { ctx[ds][0]=0.f; ctx[ds][1]=0.f; ctx[ds][2]=0.f; ctx[ds][3]=0.f; }

    const int laneA = x + 32 * (g & 1);
    const int laneB = laneA + 16;
    const int tsel  = g >> 1;

    for (int s = 0; s < 16; ++s) {
        unsigned W00, W01, W10, W11;
        #pragma unroll
        for (int u = 0; u < 2; ++u) {
            const int ktg = 32 * w + 2 * s + u;
            f32x4 c; qk_tile(ktg, c);
            const float p0 = __expf(c[0] - M) * il, p1 = __expf(c[1] - M) * il;
            const float p2 = __expf(c[2] - M) * il, p3 = __expf(c[3] - M) * il;
            float4 o; o.x = p0; o.y = p1; o.z = p2; o.w = p3;
            *(float4*)(attn_out + ((size_t)bh * S_ + q0 + x) * S_ + ktg * 16 + 4 * g) = o;
            const unsigned lo = pk_bf16(p0, p1), hi = pk_bf16(p2, p3);
            if (u == 0) { W00 = lo; W01 = hi; } else { W10 = lo; W11 = hi; }
        }
        // exchange C-layout -> PV A-fragment (keys kb + 8g + 0..7 for row q=x)
        const unsigned a00 = __shfl(W00, laneA), a10 = __shfl(W10, laneA);
        const unsigned a01 = __shfl(W01, laneA), a11 = __shfl(W11, laneA);
        const unsigned b00 = __shfl(W00, laneB), b10 = __shfl(W10, laneB);
        const unsigned b01 = __shfl(W01, laneB), b11 = __shfl(W11, laneB);
        union { unsigned u[4]; bf16x8 v; } pa;
        pa.u[0] = tsel ? a10 : a00;
        pa.u[1] = tsel ? a11 : a01;
        pa.u[2] = tsel ? b10 : b00;
        pa.u[3] = tsel ? b11 : b01;
        const int kb = 512 * w + 32 * s;
        #pragma unroll
        for (int ds = 0; ds < 4; ++ds) {
            bf16x8 vb;
            if (PREP) {
                vb = *(const bf16x8*)(Vt + ((size_t)bh * D_ + 16 * ds + x) * S_ + kb + 8 * g);
            } else {
                const float* vp = Vf + ((size_t)bh * S_ + kb + 8 * g) * D_ + 16 * ds + x;
                #pragma unroll
                for (int j = 0; j < 8; ++j) vb[j] = f2bf(vp[(size_t)j * D_]);
            }
            ctx[ds] = __builtin_amdgcn_mfma_f32_16x16x32_bf16(pa.v, vb, ctx[ds], 0, 0, 0);
        }
    }

    // ---- ctx cross-wave reduce + store ----
    #pragma unroll
    for (int ds = 0; ds < 4; ++ds)
        #pragma unroll
        for (int r = 0; r < 4; ++r)
            ctxp[w][4 * g + r][16 * ds + x] = ctx[ds][r];
    __syncthreads();
    {
        const int base = t * 4;                 // 4 cells of [16][64] per thread
        const int qr = base >> 6, c0 = base & 63;
        float4 o;
        o.x = ctxp[0][qr][c0+0] + ctxp[1][qr][c0+0] + ctxp[2][qr][c0+0] + ctxp[3][qr][c0+0];
        o.y = ctxp[0][qr][c0+1] + ctxp[1][qr][c0+1] + ctxp[2][qr][c0+1] + ctxp[3][qr][c0+1];
        o.z = ctxp[0][qr][c0+2] + ctxp[1][qr][c0+2] + ctxp[2][qr][c0+2] + ctxp[3][qr][c0+2];
        o.w = ctxp[0][qr][c0+3] + ctxp[1][qr][c0+3] + ctxp[2][qr][c0+3] + ctxp[3][qr][c0+3];
        *(float4*)(ctx_out + ((size_t)bh * S_ + q0 + qr) * D_ + c0) = o;
    }
}

extern "C" void kernel_launch(void* const* d_in, const int* in_sizes, int n_in,
                              void* d_out, int out_size, void* d_ws, size_t ws_size,
                              hipStream_t stream) {
    const float* Q = (const float*)d_in[0];
    const float* K = (const float*)d_in[1];
    const float* V = (const float*)d_in[2];
    const int*   M = (const int*)d_in[3];

    float* ctx  = (float*)d_out;
    float* attn = (float*)d_out + (size_t)B_ * H_ * S_ * D_;

    const size_t nEl     = (size_t)B_ * H_ * S_ * D_;     // 4.19M
    const size_t nBits64 = (size_t)B_ * S_ * (S_ / 64);   // 131072
    const size_t need    = nEl * 2 * 3 + nBits64 * 8;     // ~26.2 MB

    if (ws_size >= need) {
        unsigned short* Qs = (unsigned short*)d_ws;
        unsigned short* Kb = Qs + nEl;
        unsigned short* Vt = Kb + nEl;
        unsigned long long* bits = (unsigned long long*)(Vt + nEl);
        cvt_scale_kernel<<<dim3((int)(nEl / 2048)), dim3(256), 0, stream>>>(Q, Qs, 0.125f);
        cvt_scale_kernel<<<dim3((int)(nEl / 2048)), dim3(256), 0, stream>>>(K, Kb, 1.0f);
        cvtVT_kernel    <<<dim3(B_ * H_ * (S_ / 32)), dim3(256), 0, stream>>>(V, Vt);
        maskbits_kernel <<<dim3((int)(nBits64 / 128)), dim3(256), 0, stream>>>(M, bits);
        sdpa_2pass_kernel<1><<<dim3(NBLK), dim3(256), 0, stream>>>(
            Q, K, V, M, Qs, Kb, Vt, (const unsigned*)bits, ctx, attn);
    } else {
        sdpa_2pass_kernel<0><<<dim3(NBLK), dim3(256), 0, stream>>>(
            Q, K, V, M, nullptr, nullptr, nullptr, nullptr, ctx, attn);
    }
}

// Round 5
// 407.031 us; speedup vs baseline: 1.0480x; 1.0480x over previous
//
#include <hip/hip_runtime.h>
#include <math.h>

// (B,H,S,D) = (2,16,2048,64), fp32 in/out. Outputs: ctx [B,H,S,D] ++ attn [B,H,S,S].
#define B_   2
#define H_   16
#define S_   2048
#define D_   64
#define QT   16
#define NQT  (S_/QT)        // 128
#define NBLK (B_*H_*NQT)    // 4096

typedef __attribute__((ext_vector_type(8))) short  bf16x8;
typedef __attribute__((ext_vector_type(8))) unsigned short u16x8;
typedef __attribute__((ext_vector_type(4))) float  f32x4;

static __device__ __forceinline__ short f2bf(float f) {
    union { float f; unsigned u; } x; x.f = f;
    unsigned r = x.u + 0x7fffu + ((x.u >> 16) & 1u);   // RNE
    return (short)(r >> 16);
}
static __device__ __forceinline__ unsigned pk_bf16(float lo, float hi) {
    unsigned r;
    asm("v_cvt_pk_bf16_f32 %0, %1, %2" : "=v"(r) : "v"(lo), "v"(hi));
    return r;
}
static __device__ __forceinline__ float bfLo(unsigned w) {
    union { unsigned u; float f; } x; x.u = w << 16; return x.f;
}
static __device__ __forceinline__ float bfHi(unsigned w) {
    union { unsigned u; float f; } x; x.u = w & 0xffff0000u; return x.f;
}

// ---------- pre-pass: fp32 -> bf16 with scale (Q: 0.125, K: 1.0) ----------
__global__ __launch_bounds__(256) void cvt_scale_kernel(const float* __restrict__ src,
                                                        unsigned short* __restrict__ dst,
                                                        float scale) {
    const size_t i = ((size_t)blockIdx.x * 256 + threadIdx.x) * 8;
    const float4 a = *(const float4*)(src + i);
    const float4 b = *(const float4*)(src + i + 4);
    u16x8 o;
    o[0]=f2bf(a.x*scale); o[1]=f2bf(a.y*scale); o[2]=f2bf(a.z*scale); o[3]=f2bf(a.w*scale);
    o[4]=f2bf(b.x*scale); o[5]=f2bf(b.y*scale); o[6]=f2bf(b.z*scale); o[7]=f2bf(b.w*scale);
    *(u16x8*)(dst + i) = o;
}

// ---------- pre-pass: V fp32 [bh][k][d] -> bf16 transposed Vt [bh][d][k] ----------
__global__ __launch_bounds__(256) void cvtVT_kernel(const float* __restrict__ V,
                                                    unsigned short* __restrict__ Vt) {
    const int l  = threadIdx.x & 63;
    const int w  = threadIdx.x >> 6;
    const int bh = blockIdx.x >> 6;
    const int kc = (blockIdx.x & 63) * 32 + w * 8;
    const float* vp = V + ((size_t)bh * S_ + kc) * D_ + l;
    u16x8 o;
    #pragma unroll
    for (int j = 0; j < 8; ++j) o[j] = f2bf(vp[(size_t)j * D_]);
    *(u16x8*)(Vt + ((size_t)bh * D_ + l) * S_ + kc) = o;
}

// ---------- pre-pass: mask int32 -> bitmask ----------
__global__ __launch_bounds__(256) void maskbits_kernel(const int* __restrict__ M,
                                                       unsigned long long* __restrict__ bits) {
    const int w = threadIdx.x >> 6, l = threadIdx.x & 63;
    const size_t wl0 = (size_t)(blockIdx.x * 4 + w) * 32;
    for (int it = 0; it < 32; ++it) {
        const int mk = M[(wl0 + it) * 64 + l];
        const unsigned long long bm = __ballot(mk != 0);
        if (l == 0) bits[wl0 + it] = bm;
    }
}

// One-QK-pass fused attention, stores isolated from dependent loads.
// Block = 256 thr = 4 waves, 16-row q-tile; wave w owns keys [512w, 512w+512).
// Swapped QK^T: C = mfma(A=K, B=Q^T) -> lane (x=l&15 [q], g=l>>4) holds
// scores for keys 16*ktg + 4g + r (r=0..3) of row q0+x.
// Pass A: QK ONCE; masked scores cached packed-bf16 in 64 VGPRs; online (m,sum).
// B1: PV only: unpack->exp->pk->lane shuffle (R4-verified) -> mfma(P, Vt).
//     All loads complete before any global store is issued.
// Epilogue: 32 back-to-back float4 attn stores (fp32 exp recomputed from the
//     cached scores; no loads, no vmcnt waits between stores), then the LDS
//     ctx cross-wave reduce overlaps the store drain.
template<int PREP>
__global__ __launch_bounds__(256, 4)
void sdpa_1qk_kernel(const float* __restrict__ Qf, const float* __restrict__ Kf,
                     const float* __restrict__ Vf, const int* __restrict__ Mi,
                     const unsigned short* __restrict__ Qs,
                     const unsigned short* __restrict__ Kb,
                     const unsigned short* __restrict__ Vt,
                     const unsigned* __restrict__ bits,
                     float* __restrict__ ctx_out, float* __restrict__ attn_out) {
    __shared__ unsigned mb[QT][66];      // mask bits tile (padded), 4224 B
    __shared__ float red[4][QT][2];      // per-wave (m, sum), 512 B
    __shared__ float ctxp[4][QT][68];    // per-wave ctx partials (padded), 17408 B

    const int t = threadIdx.x;
    const int w = t >> 6;
    const int l = t & 63;
    const int x = l & 15;    // q row (B/C col); A key-row field; PV d-col
    const int g = l >> 4;    // 0..3

    const int orig = blockIdx.x;
    const int swz  = (orig & 7) * (NBLK / 8) + (orig >> 3);
    const int bh   = swz >> 7;
    const int qt   = swz & 127;
    const int b    = bh >> 4;
    const int q0   = qt * QT;

    if (PREP) {
        #pragma unroll
        for (int i = 0; i < 4; ++i) {
            const int flat = t * 4 + i;
            mb[flat >> 6][flat & 63] =
                bits[((size_t)b * S_ + q0 + (flat >> 6)) * 64 + (flat & 63)];
        }
    }

    // ---- Q B-fragments (col = q = x, k(d) = 8g+j / 32+8g+j) ----
    bf16x8 bq0, bq1;
    if (PREP) {
        const unsigned short* qp = Qs + ((size_t)bh * S_ + q0 + x) * D_ + g * 8;
        bq0 = *(const bf16x8*)qp;
        bq1 = *(const bf16x8*)(qp + 32);
    } else {
        const float* qp = Qf + ((size_t)bh * S_ + q0 + x) * D_ + g * 8;
        #pragma unroll
        for (int j = 0; j < 8; ++j) bq0[j] = f2bf(0.125f * qp[j]);
        #pragma unroll
        for (int j = 0; j < 8; ++j) bq1[j] = f2bf(0.125f * qp[32 + j]);
    }
    if (PREP) __syncthreads();   // mb ready

    // ---- Pass A: single QK pass; cache packed masked scores; online (m,sum) ----
    unsigned sp[64];
    float m = -INFINITY, ssum = 0.f;
    #pragma unroll
    for (int kt = 0; kt < 32; ++kt) {
        const int ktg = 32 * w + kt;
        bf16x8 ak0, ak1;
        if (PREP) {
            const unsigned short* kp = Kb + ((size_t)bh * S_ + ktg * 16 + x) * D_ + g * 8;
            ak0 = *(const bf16x8*)kp;
            ak1 = *(const bf16x8*)(kp + 32);
        } else {
            const float* kp = Kf + ((size_t)bh * S_ + ktg * 16 + x) * D_ + g * 8;
            #pragma unroll
            for (int j = 0; j < 8; ++j) ak0[j] = f2bf(kp[j]);
            #pragma unroll
            for (int j = 0; j < 8; ++j) ak1[j] = f2bf(kp[32 + j]);
        }
        f32x4 c = {0.f, 0.f, 0.f, 0.f};
        c = __builtin_amdgcn_mfma_f32_16x16x32_bf16(ak0, bq0, c, 0, 0, 0);
        c = __builtin_amdgcn_mfma_f32_16x16x32_bf16(ak1, bq1, c, 0, 0, 0);
        if (PREP) {
            const unsigned word = mb[x][ktg >> 1];
            const int base = 16 * (ktg & 1) + 4 * g;
            #pragma unroll
            for (int r = 0; r < 4; ++r)
                if (!((word >> (base + r)) & 1u)) c[r] = -1e9f;
        } else {
            const int* mp = Mi + ((size_t)b * S_ + q0 + x) * S_ + ktg * 16 + 4 * g;
            #pragma unroll
            for (int r = 0; r < 4; ++r)
                if (!mp[r]) c[r] = -1e9f;
        }
        sp[2 * kt]     = pk_bf16(c[0], c[1]);
        sp[2 * kt + 1] = pk_bf16(c[2], c[3]);
        const float tm = fmaxf(fmaxf(c[0], c[1]), fmaxf(c[2], c[3]));
        const float nm = fmaxf(m, tm);
        ssum = ssum * __expf(m - nm)
             + __expf(c[0] - nm) + __expf(c[1] - nm)
             + __expf(c[2] - nm) + __expf(c[3] - nm);
        m = nm;
    }
    #pragma unroll
    for (int off = 16; off <= 32; off <<= 1) {    // combine across g groups
        const float mo = __shfl_xor(m, off), so = __shfl_xor(ssum, off);
        const float nm = fmaxf(m, mo);
        ssum = ssum * __expf(m - nm) + so * __expf(mo - nm);
        m = nm;
    }
    if (l < 16) { red[w][l][0] = m; red[w][l][1] = ssum; }
    __syncthreads();
    float M = -INFINITY, S = 0.f;
    #pragma unroll
    for (int wv = 0; wv < 4; ++wv) {              // combine across waves
        const float mo = red[wv][x][0], so = red[wv][x][1];
        const float nm = fmaxf(M, mo);
        S = S * __expf(M - nm) + so * __expf(mo - nm);
        M = nm;
    }
    const float il = 1.0f / S;

    // ---- B1: PV only (no global stores yet) ----
    f32x4 ctx[4];
    #pragma unroll
    for (int ds = 0; ds < 4; ++ds) { ctx[ds][0]=0.f; ctx[ds][1]=0.f; ctx[ds][2]=0.f; ctx[ds][3]=0.f; }

    const int laneA = x + 32 * (g & 1);
    const int laneB = laneA + 16;
    const int tsel  = g >> 1;

    #pragma unroll
    for (int s = 0; s < 16; ++s) {
        unsigned W00, W01, W10, W11;
        #pragma unroll
        for (int u = 0; u < 2; ++u) {
            const unsigned wa = sp[4 * s + 2 * u];
            const unsigned wb = sp[4 * s + 2 * u + 1];
            const float p0 = __expf(bfLo(wa) - M) * il, p1 = __expf(bfHi(wa) - M) * il;
            const float p2 = __expf(bfLo(wb) - M) * il, p3 = __expf(bfHi(wb) - M) * il;
            const unsigned lo = pk_bf16(p0, p1), hi = pk_bf16(p2, p3);
            if (u == 0) { W00 = lo; W01 = hi; } else { W10 = lo; W11 = hi; }
        }
        // exchange C-layout -> PV A-fragment (keys kb + 8g + 0..7 for row q=x)
        const unsigned a00 = __shfl(W00, laneA), a10 = __shfl(W10, laneA);
        const unsigned a01 = __shfl(W01, laneA), a11 = __shfl(W11, laneA);
        const unsigned b00 = __shfl(W00, laneB), b10 = __shfl(W10, laneB);
        const unsigned b01 = __shfl(W01, laneB), b11 = __shfl(W11, laneB);
        union { unsigned u[4]; bf16x8 v; } pa;
        pa.u[0] = tsel ? a10 : a00;
        pa.u[1] = tsel ? a11 : a01;
        pa.u[2] = tsel ? b10 : b00;
        pa.u[3] = tsel ? b11 : b01;
        const int kb = 512 * w + 32 * s;
        #pragma unroll
        for (int ds = 0; ds < 4; ++ds) {
            bf16x8 vb;
            if (PREP) {
                vb = *(const bf16x8*)(Vt + ((size_t)bh * D_ + 16 * ds + x) * S_ + kb + 8 * g);
            } else {
                const float* vp = Vf + ((size_t)bh * S_ + kb + 8 * g) * D_ + 16 * ds + x;
                #pragma unroll
                for (int j = 0; j < 8; ++j) vb[j] = f2bf(vp[(size_t)j * D_]);
            }
            ctx[ds] = __builtin_amdgcn_mfma_f32_16x16x32_bf16(pa.v, vb, ctx[ds], 0, 0, 0);
        }
    }

    // ---- Epilogue 1: attn stores, back-to-back, no dependent loads after ----
    {
        float* arow = attn_out + ((size_t)bh * S_ + q0 + x) * S_ + 512 * w + 4 * g;
        #pragma unroll
        for (int kt = 0; kt < 32; ++kt) {
            const unsigned wa = sp[2 * kt], wb = sp[2 * kt + 1];
            float4 o;
            o.x = __expf(bfLo(wa) - M) * il;
            o.y = __expf(bfHi(wa) - M) * il;
            o.z = __expf(bfLo(wb) - M) * il;
            o.w = __expf(bfHi(wb) - M) * il;
            *(float4*)(arow + kt * 16) = o;
        }
    }

    // ---- Epilogue 2: ctx cross-wave reduce (LDS only; overlaps store drain) ----
    #pragma unroll
    for (int ds = 0; ds < 4; ++ds)
        #pragma unroll
        for (int r = 0; r < 4; ++r)
            ctxp[w][4 * g + r][16 * ds + x] = ctx[ds][r];
    __syncthreads();
    {
        const int base = t * 4;                 // 4 cells of [16][64] per thread
        const int qr = base >> 6, c0 = base & 63;
        float4 o;
        o.x = ctxp[0][qr][c0+0] + ctxp[1][qr][c0+0] + ctxp[2][qr][c0+0] + ctxp[3][qr][c0+0];
        o.y = ctxp[0][qr][c0+1] + ctxp[1][qr][c0+1] + ctxp[2][qr][c0+1] + ctxp[3][qr][c0+1];
        o.z = ctxp[0][qr][c0+2] + ctxp[1][qr][c0+2] + ctxp[2][qr][c0+2] + ctxp[3][qr][c0+2];
        o.w = ctxp[0][qr][c0+3] + ctxp[1][qr][c0+3] + ctxp[2][qr][c0+3] + ctxp[3][qr][c0+3];
        *(float4*)(ctx_out + ((size_t)bh * S_ + q0 + qr) * D_ + c0) = o;
    }
}

extern "C" void kernel_launch(void* const* d_in, const int* in_sizes, int n_in,
                              void* d_out, int out_size, void* d_ws, size_t ws_size,
                              hipStream_t stream) {
    const float* Q = (const float*)d_in[0];
    const float* K = (const float*)d_in[1];
    const float* V = (const float*)d_in[2];
    const int*   M = (const int*)d_in[3];

    float* ctx  = (float*)d_out;
    float* attn = (float*)d_out + (size_t)B_ * H_ * S_ * D_;

    const size_t nEl     = (size_t)B_ * H_ * S_ * D_;     // 4.19M
    const size_t nBits64 = (size_t)B_ * S_ * (S_ / 64);   // 131072
    const size_t need    = nEl * 2 * 3 + nBits64 * 8;     // ~26.2 MB

    if (ws_size >= need) {
        unsigned short* Qs = (unsigned short*)d_ws;
        unsigned short* Kb = Qs + nEl;
        unsigned short* Vt = Kb + nEl;
        unsigned long long* bits = (unsigned long long*)(Vt + nEl);
        cvt_scale_kernel<<<dim3((int)(nEl / 2048)), dim3(256), 0, stream>>>(Q, Qs, 0.125f);
        cvt_scale_kernel<<<dim3((int)(nEl / 2048)), dim3(256), 0, stream>>>(K, Kb, 1.0f);
        cvtVT_kernel    <<<dim3(B_ * H_ * (S_ / 32)), dim3(256), 0, stream>>>(V, Vt);
        maskbits_kernel <<<dim3((int)(nBits64 / 128)), dim3(256), 0, stream>>>(M, bits);
        sdpa_1qk_kernel<1><<<dim3(NBLK), dim3(256), 0, stream>>>(
            Q, K, V, M, Qs, Kb, Vt, (const unsigned*)bits, ctx, attn);
    } else {
        sdpa_1qk_kernel<0><<<dim3(NBLK), dim3(256), 0, stream>>>(
            Q, K, V, M, nullptr, nullptr, nullptr, nullptr, ctx, attn);
    }
}

// Round 6
// 403.280 us; speedup vs baseline: 1.0578x; 1.0093x over previous
//
#include <hip/hip_runtime.h>
#include <math.h>

// (B,H,S,D) = (2,16,2048,64), fp32 in/out. Outputs: ctx [B,H,S,D] ++ attn [B,H,S,S].
#define B_   2
#define H_   16
#define S_   2048
#define D_   64
#define QT   16
#define NQT  (S_/QT)        // 128
#define NBLK (B_*H_*NQT)    // 4096

typedef __attribute__((ext_vector_type(8))) short  bf16x8;
typedef __attribute__((ext_vector_type(8))) unsigned short u16x8;
typedef __attribute__((ext_vector_type(4))) float  f32x4;

static __device__ __forceinline__ short f2bf(float f) {
    union { float f; unsigned u; } x; x.f = f;
    unsigned r = x.u + 0x7fffu + ((x.u >> 16) & 1u);   // RNE
    return (short)(r >> 16);
}
static __device__ __forceinline__ unsigned pk_bf16(float lo, float hi) {
    unsigned r;
    asm("v_cvt_pk_bf16_f32 %0, %1, %2" : "=v"(r) : "v"(lo), "v"(hi));
    return r;
}
static __device__ __forceinline__ float bfLo(unsigned w) {
    union { unsigned u; float f; } x; x.u = w << 16; return x.f;
}
static __device__ __forceinline__ float bfHi(unsigned w) {
    union { unsigned u; float f; } x; x.u = w & 0xffff0000u; return x.f;
}

// ---------- pre-pass: fp32 -> bf16 with scale (Q: 0.125, K: 1.0) ----------
__global__ __launch_bounds__(256) void cvt_scale_kernel(const float* __restrict__ src,
                                                        unsigned short* __restrict__ dst,
                                                        float scale) {
    const size_t i = ((size_t)blockIdx.x * 256 + threadIdx.x) * 8;
    const float4 a = *(const float4*)(src + i);
    const float4 b = *(const float4*)(src + i + 4);
    u16x8 o;
    o[0]=f2bf(a.x*scale); o[1]=f2bf(a.y*scale); o[2]=f2bf(a.z*scale); o[3]=f2bf(a.w*scale);
    o[4]=f2bf(b.x*scale); o[5]=f2bf(b.y*scale); o[6]=f2bf(b.z*scale); o[7]=f2bf(b.w*scale);
    *(u16x8*)(dst + i) = o;
}

// ---------- pre-pass: V fp32 [bh][k][d] -> bf16 transposed Vt [bh][d][k] ----------
__global__ __launch_bounds__(256) void cvtVT_kernel(const float* __restrict__ V,
                                                    unsigned short* __restrict__ Vt) {
    const int l  = threadIdx.x & 63;
    const int w  = threadIdx.x >> 6;
    const int bh = blockIdx.x >> 6;
    const int kc = (blockIdx.x & 63) * 32 + w * 8;
    const float* vp = V + ((size_t)bh * S_ + kc) * D_ + l;
    u16x8 o;
    #pragma unroll
    for (int j = 0; j < 8; ++j) o[j] = f2bf(vp[(size_t)j * D_]);
    *(u16x8*)(Vt + ((size_t)bh * D_ + l) * S_ + kc) = o;
}

// ---------- pre-pass: mask int32 -> bitmask ----------
__global__ __launch_bounds__(256) void maskbits_kernel(const int* __restrict__ M,
                                                       unsigned long long* __restrict__ bits) {
    const int w = threadIdx.x >> 6, l = threadIdx.x & 63;
    const size_t wl0 = (size_t)(blockIdx.x * 4 + w) * 32;
    for (int it = 0; it < 32; ++it) {
        const int mk = M[(wl0 + it) * 64 + l];
        const unsigned long long bm = __ballot(mk != 0);
        if (l == 0) bits[wl0 + it] = bm;
    }
}

// One-QK-pass fused attention. Block = 512 thr = 8 waves, 16-row q-tile;
// wave w owns keys [256w, 256w+256)  -> sp[32] packed-bf16 score cache (was 64).
// Swapped QK^T: C = mfma(A=K, B=Q^T) -> lane (x=l&15 [q], g=l>>4) holds
// scores for keys 16*ktg + 4g + r (r=0..3) of row q0+x.
// Pass A: QK once, masked scores cached in regs, online (m,sum);
//         mask via direct L2-resident bit-word loads (no LDS tile).
// B1: PV: unpack->exp->pk->lane shuffle -> mfma(P, Vt). Loads before stores.
// Epilogue: 16 back-to-back float4 attn stores; LDS ctx cross-wave reduce.
// launch_bounds(512,2): VGPR cap 256 -- R4/R5's (256,4) caused sp[] scratch
// spill (VGPR_Count 36/64, +320MB HBM traffic); this keeps sp in registers.
template<int PREP>
__global__ __launch_bounds__(512, 2)
void sdpa_1qk_kernel(const float* __restrict__ Qf, const float* __restrict__ Kf,
                     const float* __restrict__ Vf, const int* __restrict__ Mi,
                     const unsigned short* __restrict__ Qs,
                     const unsigned short* __restrict__ Kb,
                     const unsigned short* __restrict__ Vt,
                     const unsigned* __restrict__ bits,
                     float* __restrict__ ctx_out, float* __restrict__ attn_out) {
    __shared__ float red[8][QT][2];      // per-wave (m, sum), 1 KB
    __shared__ float ctxp[8][QT][68];    // per-wave ctx partials (padded), 34.8 KB

    const int t = threadIdx.x;
    const int w = t >> 6;    // 0..7
    const int l = t & 63;
    const int x = l & 15;    // q row (B/C col); A key-row field; PV d-col
    const int g = l >> 4;    // 0..3

    const int orig = blockIdx.x;
    const int swz  = (orig & 7) * (NBLK / 8) + (orig >> 3);
    const int bh   = swz >> 7;
    const int qt   = swz & 127;
    const int b    = bh >> 4;
    const int q0   = qt * QT;

    // ---- Q B-fragments (col = q = x, k(d) = 8g+j / 32+8g+j) ----
    bf16x8 bq0, bq1;
    if (PREP) {
        const unsigned short* qp = Qs + ((size_t)bh * S_ + q0 + x) * D_ + g * 8;
        bq0 = *(const bf16x8*)qp;
        bq1 = *(const bf16x8*)(qp + 32);
    } else {
        const float* qp = Qf + ((size_t)bh * S_ + q0 + x) * D_ + g * 8;
        #pragma unroll
        for (int j = 0; j < 8; ++j) bq0[j] = f2bf(0.125f * qp[j]);
        #pragma unroll
        for (int j = 0; j < 8; ++j) bq1[j] = f2bf(0.125f * qp[32 + j]);
    }

    const unsigned* brow = PREP ? (bits + ((size_t)b * S_ + q0 + x) * 64) : nullptr;

    // ---- Pass A: single QK pass; cache packed masked scores; online (m,sum) ----
    unsigned sp[32];
    float m = -INFINITY, ssum = 0.f;
    #pragma unroll
    for (int kt = 0; kt < 16; ++kt) {
        const int ktg = 16 * w + kt;
        bf16x8 ak0, ak1;
        if (PREP) {
            const unsigned short* kp = Kb + ((size_t)bh * S_ + ktg * 16 + x) * D_ + g * 8;
            ak0 = *(const bf16x8*)kp;
            ak1 = *(const bf16x8*)(kp + 32);
        } else {
            const float* kp = Kf + ((size_t)bh * S_ + ktg * 16 + x) * D_ + g * 8;
            #pragma unroll
            for (int j = 0; j < 8; ++j) ak0[j] = f2bf(kp[j]);
            #pragma unroll
            for (int j = 0; j < 8; ++j) ak1[j] = f2bf(kp[32 + j]);
        }
        f32x4 c = {0.f, 0.f, 0.f, 0.f};
        c = __builtin_amdgcn_mfma_f32_16x16x32_bf16(ak0, bq0, c, 0, 0, 0);
        c = __builtin_amdgcn_mfma_f32_16x16x32_bf16(ak1, bq1, c, 0, 0, 0);
        if (PREP) {
            const unsigned word = brow[ktg >> 1];
            const int base = 16 * (ktg & 1) + 4 * g;
            #pragma unroll
            for (int r = 0; r < 4; ++r)
                if (!((word >> (base + r)) & 1u)) c[r] = -1e9f;
        } else {
            const int* mp = Mi + ((size_t)b * S_ + q0 + x) * S_ + ktg * 16 + 4 * g;
            #pragma unroll
            for (int r = 0; r < 4; ++r)
                if (!mp[r]) c[r] = -1e9f;
        }
        sp[2 * kt]     = pk_bf16(c[0], c[1]);
        sp[2 * kt + 1] = pk_bf16(c[2], c[3]);
        const float tm = fmaxf(fmaxf(c[0], c[1]), fmaxf(c[2], c[3]));
        const float nm = fmaxf(m, tm);
        ssum = ssum * __expf(m - nm)
             + __expf(c[0] - nm) + __expf(c[1] - nm)
             + __expf(c[2] - nm) + __expf(c[3] - nm);
        m = nm;
    }
    #pragma unroll
    for (int off = 16; off <= 32; off <<= 1) {    // combine across g groups
        const float mo = __shfl_xor(m, off), so = __shfl_xor(ssum, off);
        const float nm = fmaxf(m, mo);
        ssum = ssum * __expf(m - nm) + so * __expf(mo - nm);
        m = nm;
    }
    if (l < 16) { red[w][l][0] = m; red[w][l][1] = ssum; }
    __syncthreads();
    float M = -INFINITY, S = 0.f;
    #pragma unroll
    for (int wv = 0; wv < 8; ++wv) {              // combine across 8 waves
        const float mo = red[wv][x][0], so = red[wv][x][1];
        const float nm = fmaxf(M, mo);
        S = S * __expf(M - nm) + so * __expf(mo - nm);
        M = nm;
    }
    const float il = 1.0f / S;

    // ---- B1: PV only (no global stores yet) ----
    f32x4 ctx[4];
    #pragma unroll
    for (int ds = 0; ds < 4; ++ds) { ctx[ds][0]=0.f; ctx[ds][1]=0.f; ctx[ds][2]=0.f; ctx[ds][3]=0.f; }

    const int laneA = x + 32 * (g & 1);
    const int laneB = laneA + 16;
    const int tsel  = g >> 1;

    #pragma unroll
    for (int s = 0; s < 8; ++s) {
        unsigned W00, W01, W10, W11;
        #pragma unroll
        for (int u = 0; u < 2; ++u) {
            const unsigned wa = sp[4 * s + 2 * u];
            const unsigned wb = sp[4 * s + 2 * u + 1];
            const float p0 = __expf(bfLo(wa) - M) * il, p1 = __expf(bfHi(wa) - M) * il;
            const float p2 = __expf(bfLo(wb) - M) * il, p3 = __expf(bfHi(wb) - M) * il;
            const unsigned lo = pk_bf16(p0, p1), hi = pk_bf16(p2, p3);
            if (u == 0) { W00 = lo; W01 = hi; } else { W10 = lo; W11 = hi; }
        }
        // exchange C-layout -> PV A-fragment (keys kb + 8g + 0..7 for row q=x)
        const unsigned a00 = __shfl(W00, laneA), a10 = __shfl(W10, laneA);
        const unsigned a01 = __shfl(W01, laneA), a11 = __shfl(W11, laneA);
        const unsigned b00 = __shfl(W00, laneB), b10 = __shfl(W10, laneB);
        const unsigned b01 = __shfl(W01, laneB), b11 = __shfl(W11, laneB);
        union { unsigned u[4]; bf16x8 v; } pa;
        pa.u[0] = tsel ? a10 : a00;
        pa.u[1] = tsel ? a11 : a01;
        pa.u[2] = tsel ? b10 : b00;
        pa.u[3] = tsel ? b11 : b01;
        const int kb = 256 * w + 32 * s;
        #pragma unroll
        for (int ds = 0; ds < 4; ++ds) {
            bf16x8 vb;
            if (PREP) {
                vb = *(const bf16x8*)(Vt + ((size_t)bh * D_ + 16 * ds + x) * S_ + kb + 8 * g);
            } else {
                const float* vp = Vf + ((size_t)bh * S_ + kb + 8 * g) * D_ + 16 * ds + x;
                #pragma unroll
                for (int j = 0; j < 8; ++j) vb[j] = f2bf(vp[(size_t)j * D_]);
            }
            ctx[ds] = __builtin_amdgcn_mfma_f32_16x16x32_bf16(pa.v, vb, ctx[ds], 0, 0, 0);
        }
    }

    // ---- Epilogue 1: attn stores, back-to-back, no dependent loads after ----
    {
        float* arow = attn_out + ((size_t)bh * S_ + q0 + x) * S_ + 256 * w + 4 * g;
        #pragma unroll
        for (int kt = 0; kt < 16; ++kt) {
            const unsigned wa = sp[2 * kt], wb = sp[2 * kt + 1];
            float4 o;
            o.x = __expf(bfLo(wa) - M) * il;
            o.y = __expf(bfHi(wa) - M) * il;
            o.z = __expf(bfLo(wb) - M) * il;
            o.w = __expf(bfHi(wb) - M) * il;
            *(float4*)(arow + kt * 16) = o;
        }
    }

    // ---- Epilogue 2: ctx cross-wave reduce (LDS only; overlaps store drain) ----
    #pragma unroll
    for (int ds = 0; ds < 4; ++ds)
        #pragma unroll
        for (int r = 0; r < 4; ++r)
            ctxp[w][4 * g + r][16 * ds + x] = ctx[ds][r];
    __syncthreads();
    {
        const int base = t * 2;                 // 2 cells of [16][64] per thread
        const int qr = base >> 6, c0 = base & 63;
        float2 o;
        o.x = 0.f; o.y = 0.f;
        #pragma unroll
        for (int wv = 0; wv < 8; ++wv) {
            o.x += ctxp[wv][qr][c0];
            o.y += ctxp[wv][qr][c0 + 1];
        }
        *(float2*)(ctx_out + ((size_t)bh * S_ + q0 + qr) * D_ + c0) = o;
    }
}

extern "C" void kernel_launch(void* const* d_in, const int* in_sizes, int n_in,
                              void* d_out, int out_size, void* d_ws, size_t ws_size,
                              hipStream_t stream) {
    const float* Q = (const float*)d_in[0];
    const float* K = (const float*)d_in[1];
    const float* V = (const float*)d_in[2];
    const int*   M = (const int*)d_in[3];

    float* ctx  = (float*)d_out;
    float* attn = (float*)d_out + (size_t)B_ * H_ * S_ * D_;

    const size_t nEl     = (size_t)B_ * H_ * S_ * D_;     // 4.19M
    const size_t nBits64 = (size_t)B_ * S_ * (S_ / 64);   // 131072
    const size_t need    = nEl * 2 * 3 + nBits64 * 8;     // ~26.2 MB

    if (ws_size >= need) {
        unsigned short* Qs = (unsigned short*)d_ws;
        unsigned short* Kb = Qs + nEl;
        unsigned short* Vt = Kb + nEl;
        unsigned long long* bits = (unsigned long long*)(Vt + nEl);
        cvt_scale_kernel<<<dim3((int)(nEl / 2048)), dim3(256), 0, stream>>>(Q, Qs, 0.125f);
        cvt_scale_kernel<<<dim3((int)(nEl / 2048)), dim3(256), 0, stream>>>(K, Kb, 1.0f);
        cvtVT_kernel    <<<dim3(B_ * H_ * (S_ / 32)), dim3(256), 0, stream>>>(V, Vt);
        maskbits_kernel <<<dim3((int)(nBits64 / 128)), dim3(256), 0, stream>>>(M, bits);
        sdpa_1qk_kernel<1><<<dim3(NBLK), dim3(512), 0, stream>>>(
            Q, K, V, M, Qs, Kb, Vt, (const unsigned*)bits, ctx, attn);
    } else {
        sdpa_1qk_kernel<0><<<dim3(NBLK), dim3(512), 0, stream>>>(
            Q, K, V, M, nullptr, nullptr, nullptr, nullptr, ctx, attn);
    }
}

// Round 8
// 375.352 us; speedup vs baseline: 1.1365x; 1.0744x over previous
//
#include <hip/hip_runtime.h>
#include <math.h>

// (B,H,S,D) = (2,16,2048,64), fp32 in/out. Outputs: ctx [B,H,S,D] ++ attn [B,H,S,S].
#define B_   2
#define H_   16
#define S_   2048
#define D_   64
#define QT   16
#define NQT  (S_/QT)        // 128
#define NBLK (B_*H_*NQT)    // 4096

typedef __attribute__((ext_vector_type(8))) short  bf16x8;
typedef __attribute__((ext_vector_type(8))) unsigned short u16x8;
typedef __attribute__((ext_vector_type(4))) float  f32x4;
typedef __attribute__((ext_vector_type(2))) float  f32x2;

static __device__ __forceinline__ short f2bf(float f) {
    union { float f; unsigned u; } x; x.f = f;
    unsigned r = x.u + 0x7fffu + ((x.u >> 16) & 1u);   // RNE
    return (short)(r >> 16);
}
static __device__ __forceinline__ unsigned pk_bf16(float lo, float hi) {
    unsigned r;
    asm("v_cvt_pk_bf16_f32 %0, %1, %2" : "=v"(r) : "v"(lo), "v"(hi));
    return r;
}
static __device__ __forceinline__ float bfLo(unsigned w) {
    union { unsigned u; float f; } x; x.u = w << 16; return x.f;
}
static __device__ __forceinline__ float bfHi(unsigned w) {
    union { unsigned u; float f; } x; x.u = w & 0xffff0000u; return x.f;
}

// ---------- pre-pass: fp32 -> bf16 with scale (Q: 0.125, K: 1.0) ----------
__global__ __launch_bounds__(256) void cvt_scale_kernel(const float* __restrict__ src,
                                                        unsigned short* __restrict__ dst,
                                                        float scale) {
    const size_t i = ((size_t)blockIdx.x * 256 + threadIdx.x) * 8;
    const float4 a = *(const float4*)(src + i);
    const float4 b = *(const float4*)(src + i + 4);
    u16x8 o;
    o[0]=f2bf(a.x*scale); o[1]=f2bf(a.y*scale); o[2]=f2bf(a.z*scale); o[3]=f2bf(a.w*scale);
    o[4]=f2bf(b.x*scale); o[5]=f2bf(b.y*scale); o[6]=f2bf(b.z*scale); o[7]=f2bf(b.w*scale);
    *(u16x8*)(dst + i) = o;
}

// ---------- pre-pass: V fp32 [bh][k][d] -> bf16 transposed Vt [bh][d][k] ----------
__global__ __launch_bounds__(256) void cvtVT_kernel(const float* __restrict__ V,
                                                    unsigned short* __restrict__ Vt) {
    const int l  = threadIdx.x & 63;
    const int w  = threadIdx.x >> 6;
    const int bh = blockIdx.x >> 6;
    const int kc = (blockIdx.x & 63) * 32 + w * 8;
    const float* vp = V + ((size_t)bh * S_ + kc) * D_ + l;
    u16x8 o;
    #pragma unroll
    for (int j = 0; j < 8; ++j) o[j] = f2bf(vp[(size_t)j * D_]);
    *(u16x8*)(Vt + ((size_t)bh * D_ + l) * S_ + kc) = o;
}

// ---------- pre-pass: mask int32 -> bitmask ----------
__global__ __launch_bounds__(256) void maskbits_kernel(const int* __restrict__ M,
                                                       unsigned long long* __restrict__ bits) {
    const int w = threadIdx.x >> 6, l = threadIdx.x & 63;
    const size_t wl0 = (size_t)(blockIdx.x * 4 + w) * 32;
    for (int it = 0; it < 32; ++it) {
        const int mk = M[(wl0 + it) * 64 + l];
        const unsigned long long bm = __ballot(mk != 0);
        if (l == 0) bits[wl0 + it] = bm;
    }
}

// One-QK-pass fused attention. Block = 512 thr = 8 waves, 16-row q-tile;
// wave w owns keys [256w, 256w+256) -> sp[32] packed-bf16 score cache.
// R7/R8 change (single variable vs R6): attn/ctx stores are NONTEMPORAL.
// Theory: the 540MB attn write stream thrashes the 4MB/XCD L2 (write-allocate),
// evicting the K/Vt working set -> every load becomes an ~1000cyc HBM miss ->
// all pipes idle (R6: VALU 24%, MFMA 3.8%, HBM 19%, waves ~93% stalled).
// nt stores stream past L2 and keep K/Vt resident.
template<int PREP>
__global__ __launch_bounds__(512, 2)
void sdpa_1qk_kernel(const float* __restrict__ Qf, const float* __restrict__ Kf,
                     const float* __restrict__ Vf, const int* __restrict__ Mi,
                     const unsigned short* __restrict__ Qs,
                     const unsigned short* __restrict__ Kb,
                     const unsigned short* __restrict__ Vt,
                     const unsigned* __restrict__ bits,
                     float* __restrict__ ctx_out, float* __restrict__ attn_out) {
    __shared__ float red[8][QT][2];      // per-wave (m, sum), 1 KB
    __shared__ float ctxp[8][QT][68];    // per-wave ctx partials (padded), 34.8 KB

    const int t = threadIdx.x;
    const int w = t >> 6;    // 0..7
    const int l = t & 63;
    const int x = l & 15;    // q row (B/C col); A key-row field; PV d-col
    const int g = l >> 4;    // 0..3

    const int orig = blockIdx.x;
    const int swz  = (orig & 7) * (NBLK / 8) + (orig >> 3);
    const int bh   = swz >> 7;
    const int qt   = swz & 127;
    const int b    = bh >> 4;
    const int q0   = qt * QT;

    // ---- Q B-fragments (col = q = x, k(d) = 8g+j / 32+8g+j) ----
    bf16x8 bq0, bq1;
    if (PREP) {
        const unsigned short* qp = Qs + ((size_t)bh * S_ + q0 + x) * D_ + g * 8;
        bq0 = *(const bf16x8*)qp;
        bq1 = *(const bf16x8*)(qp + 32);
    } else {
        const float* qp = Qf + ((size_t)bh * S_ + q0 + x) * D_ + g * 8;
        #pragma unroll
        for (int j = 0; j < 8; ++j) bq0[j] = f2bf(0.125f * qp[j]);
        #pragma unroll
        for (int j = 0; j < 8; ++j) bq1[j] = f2bf(0.125f * qp[32 + j]);
    }

    const unsigned* brow = PREP ? (bits + ((size_t)b * S_ + q0 + x) * 64) : nullptr;

    // ---- Pass A: single QK pass; cache packed masked scores; online (m,sum) ----
    unsigned sp[32];
    float m = -INFINITY, ssum = 0.f;
    #pragma unroll
    for (int kt = 0; kt < 16; ++kt) {
        const int ktg = 16 * w + kt;
        bf16x8 ak0, ak1;
        if (PREP) {
            const unsigned short* kp = Kb + ((size_t)bh * S_ + ktg * 16 + x) * D_ + g * 8;
            ak0 = *(const bf16x8*)kp;
            ak1 = *(const bf16x8*)(kp + 32);
        } else {
            const float* kp = Kf + ((size_t)bh * S_ + ktg * 16 + x) * D_ + g * 8;
            #pragma unroll
            for (int j = 0; j < 8; ++j) ak0[j] = f2bf(kp[j]);
            #pragma unroll
            for (int j = 0; j < 8; ++j) ak1[j] = f2bf(kp[32 + j]);
        }
        f32x4 c = {0.f, 0.f, 0.f, 0.f};
        c = __builtin_amdgcn_mfma_f32_16x16x32_bf16(ak0, bq0, c, 0, 0, 0);
        c = __builtin_amdgcn_mfma_f32_16x16x32_bf16(ak1, bq1, c, 0, 0, 0);
        if (PREP) {
            const unsigned word = brow[ktg >> 1];
            const int base = 16 * (ktg & 1) + 4 * g;
            #pragma unroll
            for (int r = 0; r < 4; ++r)
                if (!((word >> (base + r)) & 1u)) c[r] = -1e9f;
        } else {
            const int* mp = Mi + ((size_t)b * S_ + q0 + x) * S_ + ktg * 16 + 4 * g;
            #pragma unroll
            for (int r = 0; r < 4; ++r)
                if (!mp[r]) c[r] = -1e9f;
        }
        sp[2 * kt]     = pk_bf16(c[0], c[1]);
        sp[2 * kt + 1] = pk_bf16(c[2], c[3]);
        const float tm = fmaxf(fmaxf(c[0], c[1]), fmaxf(c[2], c[3]));
        const float nm = fmaxf(m, tm);
        ssum = ssum * __expf(m - nm)
             + __expf(c[0] - nm) + __expf(c[1] - nm)
             + __expf(c[2] - nm) + __expf(c[3] - nm);
        m = nm;
    }
    #pragma unroll
    for (int off = 16; off <= 32; off <<= 1) {    // combine across g groups
        const float mo = __shfl_xor(m, off), so = __shfl_xor(ssum, off);
        const float nm = fmaxf(m, mo);
        ssum = ssum * __expf(m - nm) + so * __expf(mo - nm);
        m = nm;
    }
    if (l < 16) { red[w][l][0] = m; red[w][l][1] = ssum; }
    __syncthreads();
    float M = -INFINITY, S = 0.f;
    #pragma unroll
    for (int wv = 0; wv < 8; ++wv) {              // combine across 8 waves
        const float mo = red[wv][x][0], so = red[wv][x][1];
        const float nm = fmaxf(M, mo);
        S = S * __expf(M - nm) + so * __expf(mo - nm);
        M = nm;
    }
    const float il = 1.0f / S;

    // ---- B1: PV only (no global stores yet) ----
    f32x4 ctx[4];
    #pragma unroll
    for (int ds = 0; ds < 4; ++ds) { ctx[ds][0]=0.f; ctx[ds][1]=0.f; ctx[ds][2]=0.f; ctx[ds][3]=0.f; }

    const int laneA = x + 32 * (g & 1);
    const int laneB = laneA + 16;
    const int tsel  = g >> 1;

    #pragma unroll
    for (int s = 0; s < 8; ++s) {
        unsigned W00, W01, W10, W11;
        #pragma unroll
        for (int u = 0; u < 2; ++u) {
            const unsigned wa = sp[4 * s + 2 * u];
            const unsigned wb = sp[4 * s + 2 * u + 1];
            const float p0 = __expf(bfLo(wa) - M) * il, p1 = __expf(bfHi(wa) - M) * il;
            const float p2 = __expf(bfLo(wb) - M) * il, p3 = __expf(bfHi(wb) - M) * il;
            const unsigned lo = pk_bf16(p0, p1), hi = pk_bf16(p2, p3);
            if (u == 0) { W00 = lo; W01 = hi; } else { W10 = lo; W11 = hi; }
        }
        // exchange C-layout -> PV A-fragment (keys kb + 8g + 0..7 for row q=x)
        const unsigned a00 = __shfl(W00, laneA), a10 = __shfl(W10, laneA);
        const unsigned a01 = __shfl(W01, laneA), a11 = __shfl(W11, laneA);
        const unsigned b00 = __shfl(W00, laneB), b10 = __shfl(W10, laneB);
        const unsigned b01 = __shfl(W01, laneB), b11 = __shfl(W11, laneB);
        union { unsigned u[4]; bf16x8 v; } pa;
        pa.u[0] = tsel ? a10 : a00;
        pa.u[1] = tsel ? a11 : a01;
        pa.u[2] = tsel ? b10 : b00;
        pa.u[3] = tsel ? b11 : b01;
        const int kb = 256 * w + 32 * s;
        #pragma unroll
        for (int ds = 0; ds < 4; ++ds) {
            bf16x8 vb;
            if (PREP) {
                vb = *(const bf16x8*)(Vt + ((size_t)bh * D_ + 16 * ds + x) * S_ + kb + 8 * g);
            } else {
                const float* vp = Vf + ((size_t)bh * S_ + kb + 8 * g) * D_ + 16 * ds + x;
                #pragma unroll
                for (int j = 0; j < 8; ++j) vb[j] = f2bf(vp[(size_t)j * D_]);
            }
            ctx[ds] = __builtin_amdgcn_mfma_f32_16x16x32_bf16(pa.v, vb, ctx[ds], 0, 0, 0);
        }
    }

    // ---- Epilogue 1: attn stores (NONTEMPORAL: stream past L2) ----
    {
        float* arow = attn_out + ((size_t)bh * S_ + q0 + x) * S_ + 256 * w + 4 * g;
        #pragma unroll
        for (int kt = 0; kt < 16; ++kt) {
            const unsigned wa = sp[2 * kt], wb = sp[2 * kt + 1];
            f32x4 o;
            o[0] = __expf(bfLo(wa) - M) * il;
            o[1] = __expf(bfHi(wa) - M) * il;
            o[2] = __expf(bfLo(wb) - M) * il;
            o[3] = __expf(bfHi(wb) - M) * il;
            __builtin_nontemporal_store(o, (f32x4*)(arow + kt * 16));
        }
    }

    // ---- Epilogue 2: ctx cross-wave reduce (LDS only; overlaps store drain) ----
    #pragma unroll
    for (int ds = 0; ds < 4; ++ds)
        #pragma unroll
        for (int r = 0; r < 4; ++r)
            ctxp[w][4 * g + r][16 * ds + x] = ctx[ds][r];
    __syncthreads();
    {
        const int base = t * 2;                 // 2 cells of [16][64] per thread
        const int qr = base >> 6, c0 = base & 63;
        f32x2 o;
        o[0] = 0.f; o[1] = 0.f;
        #pragma unroll
        for (int wv = 0; wv < 8; ++wv) {
            o[0] += ctxp[wv][qr][c0];
            o[1] += ctxp[wv][qr][c0 + 1];
        }
        __builtin_nontemporal_store(o, (f32x2*)(ctx_out + ((size_t)bh * S_ + q0 + qr) * D_ + c0));
    }
}

extern "C" void kernel_launch(void* const* d_in, const int* in_sizes, int n_in,
                              void* d_out, int out_size, void* d_ws, size_t ws_size,
                              hipStream_t stream) {
    const float* Q = (const float*)d_in[0];
    const float* K = (const float*)d_in[1];
    const float* V = (const float*)d_in[2];
    const int*   M = (const int*)d_in[3];

    float* ctx  = (float*)d_out;
    float* attn = (float*)d_out + (size_t)B_ * H_ * S_ * D_;

    const size_t nEl     = (size_t)B_ * H_ * S_ * D_;     // 4.19M
    const size_t nBits64 = (size_t)B_ * S_ * (S_ / 64);   // 131072
    const size_t need    = nEl * 2 * 3 + nBits64 * 8;     // ~26.2 MB

    if (ws_size >= need) {
        unsigned short* Qs = (unsigned short*)d_ws;
        unsigned short* Kb = Qs + nEl;
        unsigned short* Vt = Kb + nEl;
        unsigned long long* bits = (unsigned long long*)(Vt + nEl);
        cvt_scale_kernel<<<dim3((int)(nEl / 2048)), dim3(256), 0, stream>>>(Q, Qs, 0.125f);
        cvt_scale_kernel<<<dim3((int)(nEl / 2048)), dim3(256), 0, stream>>>(K, Kb, 1.0f);
        cvtVT_kernel    <<<dim3(B_ * H_ * (S_ / 32)), dim3(256), 0, stream>>>(V, Vt);
        maskbits_kernel <<<dim3((int)(nBits64 / 128)), dim3(256), 0, stream>>>(M, bits);
        sdpa_1qk_kernel<1><<<dim3(NBLK), dim3(512), 0, stream>>>(
            Q, K, V, M, Qs, Kb, Vt, (const unsigned*)bits, ctx, attn);
    } else {
        sdpa_1qk_kernel<0><<<dim3(NBLK), dim3(512), 0, stream>>>(
            Q, K, V, M, nullptr, nullptr, nullptr, nullptr, ctx, attn);
    }
}